// Round 1
// baseline (88.354 us; speedup 1.0000x reference)
//
#include <hip/hip_runtime.h>

// GMM diagonal-covariance mixture log-likelihood.
// x:[N,3] fp32, means:[16,3], covariances:[16,3], weights:[16] -> out:[N] fp32
// Memory-bound: 24 MB read + 8 MB write => ~5 us floor at 6.3 TB/s.

constexpr int KCOMP = 16;
constexpr float EPS = 1e-6f;

__global__ __launch_bounds__(256) void gmm_loglik_kernel(
    const float* __restrict__ x,
    const float* __restrict__ means,
    const float* __restrict__ cov,
    const float* __restrict__ weights,
    float* __restrict__ out,
    int n)
{
    __shared__ float s_m0[KCOMP], s_m1[KCOMP], s_m2[KCOMP];
    __shared__ float s_h0[KCOMP], s_h1[KCOMP], s_h2[KCOMP];
    __shared__ float s_c[KCOMP];

    const int t = threadIdx.x;
    if (t < KCOMP) {
        float v0 = cov[t * 3 + 0] + EPS;
        float v1 = cov[t * 3 + 1] + EPS;
        float v2 = cov[t * 3 + 2] + EPS;
        s_m0[t] = means[t * 3 + 0];
        s_m1[t] = means[t * 3 + 1];
        s_m2[t] = means[t * 3 + 2];
        s_h0[t] = 0.5f / v0;   // fold the -0.5 factor into the quadratic form
        s_h1[t] = 0.5f / v1;
        s_h2[t] = 0.5f / v2;
        // const_k = -0.5*D*log(2pi) - 0.5*sum(log v) + log(w_k)
        s_c[t] = -2.7568155996140185f
                 - 0.5f * (__logf(v0) + __logf(v1) + __logf(v2))
                 + __logf(weights[t]);
    }
    __syncthreads();

    const int ngrp = n >> 2;                    // groups of 4 points (48 B)
    const float4* __restrict__ x4 = (const float4*)x;
    float4* __restrict__ out4 = (float4*)out;
    const int stride = gridDim.x * blockDim.x;

    for (int g = blockIdx.x * blockDim.x + t; g < ngrp; g += stride) {
        float4 a = x4[3 * g + 0];
        float4 b = x4[3 * g + 1];
        float4 c = x4[3 * g + 2];
        // 4 points packed in 3 float4s
        float px[4] = {a.x, a.w, b.z, c.y};
        float py[4] = {a.y, b.x, b.w, c.z};
        float pz[4] = {a.z, b.y, c.x, c.w};
        float res[4];
#pragma unroll
        for (int p = 0; p < 4; ++p) {
            float lp[KCOMP];
            float mx = -3.4e38f;
#pragma unroll
            for (int k = 0; k < KCOMP; ++k) {
                float dx = px[p] - s_m0[k];
                float dy = py[p] - s_m1[k];
                float dz = pz[p] - s_m2[k];
                float q = dx * dx * s_h0[k];
                q += dy * dy * s_h1[k];
                q += dz * dz * s_h2[k];
                lp[k] = s_c[k] - q;
                mx = fmaxf(mx, lp[k]);
            }
            float s = 0.f;
#pragma unroll
            for (int k = 0; k < KCOMP; ++k)
                s += __expf(lp[k] - mx);
            res[p] = mx + __logf(s);
        }
        out4[g] = make_float4(res[0], res[1], res[2], res[3]);
    }

    // tail: n not a multiple of 4 (not hit for N=2,000,000, kept for safety)
    const int tail_start = ngrp << 2;
    for (int i = tail_start + blockIdx.x * blockDim.x + t; i < n; i += stride) {
        float px = x[3 * i + 0], py = x[3 * i + 1], pz = x[3 * i + 2];
        float lp[KCOMP];
        float mx = -3.4e38f;
#pragma unroll
        for (int k = 0; k < KCOMP; ++k) {
            float dx = px - s_m0[k];
            float dy = py - s_m1[k];
            float dz = pz - s_m2[k];
            float q = dx * dx * s_h0[k] + dy * dy * s_h1[k] + dz * dz * s_h2[k];
            lp[k] = s_c[k] - q;
            mx = fmaxf(mx, lp[k]);
        }
        float s = 0.f;
#pragma unroll
        for (int k = 0; k < KCOMP; ++k)
            s += __expf(lp[k] - mx);
        out[i] = mx + __logf(s);
    }
}

extern "C" void kernel_launch(void* const* d_in, const int* in_sizes, int n_in,
                              void* d_out, int out_size, void* d_ws, size_t ws_size,
                              hipStream_t stream) {
    const float* x       = (const float*)d_in[0];
    const float* means   = (const float*)d_in[1];
    const float* cov     = (const float*)d_in[2];
    const float* weights = (const float*)d_in[3];
    float* out           = (float*)d_out;

    const int n = in_sizes[0] / 3;          // number of points
    const int ngrp = n >> 2;
    int blocks = (ngrp + 255) / 256;
    if (blocks < 1) blocks = 1;

    gmm_loglik_kernel<<<blocks, 256, 0, stream>>>(x, means, cov, weights, out, n);
}

// Round 2
// 84.486 us; speedup vs baseline: 1.0458x; 1.0458x over previous
//
#include <hip/hip_runtime.h>

// GMM diagonal-covariance mixture log-likelihood.
// x:[N,3] fp32, means:[16,3], cov:[16,3], weights:[16] -> out:[N] fp32
// Roofline: 24 MB read + 8 MB write => ~5 us at 6.3 TB/s; VALU ~5 us. Balanced.
//
// Per-component log-prob in log2 units as a polynomial:
//   lp2_k = A + Bx + Cy + Dz + E*x^2 + F*y^2 + G*z^2   (6 FMA + 1 max)
// coefficients premultiplied by log2(e) so softmax uses raw v_exp_f32/v_log_f32.

constexpr int KCOMP = 16;
constexpr float EPS = 1e-6f;
#define LOG2E 1.4426950408889634f
#define LN2   0.6931471805599453f

__global__ __launch_bounds__(256) void gmm_loglik_kernel(
    const float* __restrict__ x,
    const float* __restrict__ means,
    const float* __restrict__ cov,
    const float* __restrict__ weights,
    float* __restrict__ out,
    int ngrp)                      // n/4 groups of 4 points
{
    // [k][0] = (A, Bx, By, Bz), [k][1] = (Ex, Ey, Ez, 0) -- 2x ds_read_b128/k
    __shared__ float4 s_cf[KCOMP * 2];

    const int t = threadIdx.x;
    if (t < KCOMP) {
        float v0 = cov[3 * t + 0] + EPS;
        float v1 = cov[3 * t + 1] + EPS;
        float v2 = cov[3 * t + 2] + EPS;
        float m0 = means[3 * t + 0];
        float m1 = means[3 * t + 1];
        float m2 = means[3 * t + 2];
        float h0 = 0.5f / v0, h1 = 0.5f / v1, h2 = 0.5f / v2;
        // ck = -1.5*ln(2pi) - 0.5*sum(ln v) + ln(w)
        float ck = -2.7568155996140185f
                 - 0.5f * (__logf(v0) + __logf(v1) + __logf(v2))
                 + __logf(weights[t]);
        float A = ck - (h0 * m0 * m0 + h1 * m1 * m1 + h2 * m2 * m2);
        s_cf[2 * t + 0] = make_float4(LOG2E * A,
                                      LOG2E * 2.f * h0 * m0,
                                      LOG2E * 2.f * h1 * m1,
                                      LOG2E * 2.f * h2 * m2);
        s_cf[2 * t + 1] = make_float4(-LOG2E * h0, -LOG2E * h1, -LOG2E * h2, 0.f);
    }
    __syncthreads();

    const int g = blockIdx.x * blockDim.x + t;
    if (g >= ngrp) return;

    const float4* __restrict__ x4 = (const float4*)x;
    float4 a = x4[3 * g + 0];
    float4 b = x4[3 * g + 1];
    float4 c = x4[3 * g + 2];

    // 4 points packed in 3 float4s
    float px[4] = {a.x, a.w, b.z, c.y};
    float py[4] = {a.y, b.x, b.w, c.z};
    float pz[4] = {a.z, b.y, c.x, c.w};
    float res[4];

#pragma unroll
    for (int p = 0; p < 4; ++p) {
        const float X = px[p], Y = py[p], Z = pz[p];
        const float X2 = X * X, Y2 = Y * Y, Z2 = Z * Z;
        float lp[KCOMP];
        float mx = -3.4e38f;
#pragma unroll
        for (int k = 0; k < KCOMP; ++k) {
            float4 u = s_cf[2 * k + 0];     // broadcast ds_read_b128
            float4 v = s_cf[2 * k + 1];
            float q = fmaf(u.y, X, u.x);
            q = fmaf(u.z, Y, q);
            q = fmaf(u.w, Z, q);
            q = fmaf(v.x, X2, q);
            q = fmaf(v.y, Y2, q);
            q = fmaf(v.z, Z2, q);
            lp[k] = q;
            mx = fmaxf(mx, q);
        }
        float s = 0.f;
#pragma unroll
        for (int k = 0; k < KCOMP; ++k)
            s += exp2f(lp[k] - mx);          // v_exp_f32, log2e pre-folded
        res[p] = LN2 * (mx + log2f(s));      // v_log_f32
    }

    ((float4*)out)[g] = make_float4(res[0], res[1], res[2], res[3]);
}

// scalar tail (only launched if n % 4 != 0 -- not hit for N=2,000,000)
__global__ void gmm_tail_kernel(
    const float* __restrict__ x,
    const float* __restrict__ means,
    const float* __restrict__ cov,
    const float* __restrict__ weights,
    float* __restrict__ out,
    int start, int n)
{
    int i = start + blockIdx.x * blockDim.x + threadIdx.x;
    if (i >= n) return;
    float X = x[3 * i], Y = x[3 * i + 1], Z = x[3 * i + 2];
    float lp[KCOMP];
    float mx = -3.4e38f;
#pragma unroll
    for (int k = 0; k < KCOMP; ++k) {
        float v0 = cov[3 * k] + EPS, v1 = cov[3 * k + 1] + EPS, v2 = cov[3 * k + 2] + EPS;
        float dx = X - means[3 * k], dy = Y - means[3 * k + 1], dz = Z - means[3 * k + 2];
        float q = -2.7568155996140185f
                - 0.5f * (__logf(v0) + __logf(v1) + __logf(v2))
                + __logf(weights[k])
                - 0.5f * (dx * dx / v0 + dy * dy / v1 + dz * dz / v2);
        lp[k] = q;
        mx = fmaxf(mx, q);
    }
    float s = 0.f;
#pragma unroll
    for (int k = 0; k < KCOMP; ++k)
        s += __expf(lp[k] - mx);
    out[i] = mx + __logf(s);
}

extern "C" void kernel_launch(void* const* d_in, const int* in_sizes, int n_in,
                              void* d_out, int out_size, void* d_ws, size_t ws_size,
                              hipStream_t stream) {
    const float* x       = (const float*)d_in[0];
    const float* means   = (const float*)d_in[1];
    const float* cov     = (const float*)d_in[2];
    const float* weights = (const float*)d_in[3];
    float* out           = (float*)d_out;

    const int n = in_sizes[0] / 3;
    const int ngrp = n >> 2;
    if (ngrp > 0) {
        int blocks = (ngrp + 255) / 256;
        gmm_loglik_kernel<<<blocks, 256, 0, stream>>>(x, means, cov, weights, out, ngrp);
    }
    const int rem = n - (ngrp << 2);
    if (rem > 0) {
        gmm_tail_kernel<<<1, 64, 0, stream>>>(x, means, cov, weights, out, ngrp << 2, n);
    }
}

// Round 3
// 82.452 us; speedup vs baseline: 1.0716x; 1.0247x over previous
//
#include <hip/hip_runtime.h>

// GMM diagonal-covariance mixture log-likelihood.
// x:[N,3] fp32, means:[16,3], cov:[16,3], weights:[16] -> out:[N] fp32
// Roofline: 24 MB read + 8 MB write => ~5.1 us at 6.3 TB/s. VALU ~4 us with
// packed fp32. Kernel target ~6 us; dur_us beyond that is harness poison/restore.
//
// Per-component log-prob in log2 units as a polynomial (coeffs premultiplied
// by log2(e), so softmax uses raw v_exp_f32 / v_log_f32):
//   lp2_k = A + Bx*x + By*y + Bz*z + Ex*x^2 + Ey*y^2 + Ez*z^2
// Two points computed per v2f lane-pair -> v_pk_fma_f32.

constexpr int KCOMP = 16;
constexpr float EPS = 1e-6f;
#define LOG2E 1.4426950408889634f
#define LN2   0.6931471805599453f

typedef float v2f __attribute__((ext_vector_type(2)));
static __device__ __forceinline__ v2f sp(float s) { return (v2f){s, s}; }

__global__ __launch_bounds__(256) void gmm_loglik_kernel(
    const float* __restrict__ x,
    const float* __restrict__ means,
    const float* __restrict__ cov,
    const float* __restrict__ weights,
    float* __restrict__ out,
    int nmain)                         // multiple of 4
{
    __shared__ float4 s_pts4[768];     // 1024 points AoS (12 KB), staged coalesced
    __shared__ float4 s_u[KCOMP];      // (A, Bx, By, Bz) * log2e
    __shared__ float4 s_v[KCOMP];      // (Ex, Ey, Ez, 0) * log2e

    const int t = threadIdx.x;
    if (t < KCOMP) {
        float v0 = cov[3 * t + 0] + EPS;
        float v1 = cov[3 * t + 1] + EPS;
        float v2 = cov[3 * t + 2] + EPS;
        float m0 = means[3 * t + 0];
        float m1 = means[3 * t + 1];
        float m2 = means[3 * t + 2];
        float h0 = 0.5f / v0, h1 = 0.5f / v1, h2 = 0.5f / v2;
        // ck = -1.5*ln(2pi) - 0.5*sum(ln v) + ln(w)
        float ck = -2.7568155996140185f
                 - 0.5f * (__logf(v0) + __logf(v1) + __logf(v2))
                 + __logf(weights[t]);
        float A = ck - (h0 * m0 * m0 + h1 * m1 * m1 + h2 * m2 * m2);
        s_u[t] = make_float4(LOG2E * A,
                             LOG2E * 2.f * h0 * m0,
                             LOG2E * 2.f * h1 * m1,
                             LOG2E * 2.f * h2 * m2);
        s_v[t] = make_float4(-LOG2E * h0, -LOG2E * h1, -LOG2E * h2, 0.f);
    }

    // ---- stage 1024 points (768 float4) with unit-stride coalesced loads ----
    const float4* __restrict__ x4 = (const float4*)x;
    const int n4 = (nmain >> 2) * 3;           // total float4s in main region
    const int base4 = blockIdx.x * 768;
#pragma unroll
    for (int j = 0; j < 3; ++j) {
        int idx4 = base4 + j * 256 + t;
        if (idx4 < n4) s_pts4[j * 256 + t] = x4[idx4];
    }
    __syncthreads();

    const int gp = blockIdx.x * 1024 + 4 * t;  // this thread's first point
    if (gp >= nmain) return;

    float4 c0 = s_pts4[3 * t + 0];
    float4 c1 = s_pts4[3 * t + 1];
    float4 c2 = s_pts4[3 * t + 2];
    // 4 points: (c0.x,c0.y,c0.z) (c0.w,c1.x,c1.y) (c1.z,c1.w,c2.x) (c2.y,c2.z,c2.w)
    v2f Xa = {c0.x, c0.w}, Ya = {c0.y, c1.x}, Za = {c0.z, c1.y};
    v2f Xb = {c1.z, c2.y}, Yb = {c1.w, c2.z}, Zb = {c2.x, c2.w};
    v2f X2a = Xa * Xa, Y2a = Ya * Ya, Z2a = Za * Za;
    v2f X2b = Xb * Xb, Y2b = Yb * Yb, Z2b = Zb * Zb;

    v2f lpa[KCOMP], lpb[KCOMP];
    v2f mxa = sp(-3.4e38f), mxb = sp(-3.4e38f);
#pragma unroll
    for (int k = 0; k < KCOMP; ++k) {
        float4 u = s_u[k];                     // broadcast LDS reads, hoisted
        float4 v = s_v[k];
        v2f qa = __builtin_elementwise_fma(sp(u.y), Xa, sp(u.x));
        qa = __builtin_elementwise_fma(sp(u.z), Ya, qa);
        qa = __builtin_elementwise_fma(sp(u.w), Za, qa);
        qa = __builtin_elementwise_fma(sp(v.x), X2a, qa);
        qa = __builtin_elementwise_fma(sp(v.y), Y2a, qa);
        qa = __builtin_elementwise_fma(sp(v.z), Z2a, qa);
        lpa[k] = qa;
        mxa = __builtin_elementwise_max(mxa, qa);

        v2f qb = __builtin_elementwise_fma(sp(u.y), Xb, sp(u.x));
        qb = __builtin_elementwise_fma(sp(u.z), Yb, qb);
        qb = __builtin_elementwise_fma(sp(u.w), Zb, qb);
        qb = __builtin_elementwise_fma(sp(v.x), X2b, qb);
        qb = __builtin_elementwise_fma(sp(v.y), Y2b, qb);
        qb = __builtin_elementwise_fma(sp(v.z), Z2b, qb);
        lpb[k] = qb;
        mxb = __builtin_elementwise_max(mxb, qb);
    }

    v2f sa = sp(0.f), sb = sp(0.f);
#pragma unroll
    for (int k = 0; k < KCOMP; ++k) {
        v2f da = lpa[k] - mxa;                 // packed subs
        v2f db = lpb[k] - mxb;
        sa.x += __builtin_amdgcn_exp2f(da.x);  // native v_exp_f32
        sa.y += __builtin_amdgcn_exp2f(da.y);
        sb.x += __builtin_amdgcn_exp2f(db.x);
        sb.y += __builtin_amdgcn_exp2f(db.y);
    }

    float4 res;
    res.x = LN2 * (mxa.x + __builtin_amdgcn_logf(sa.x));   // native v_log_f32
    res.y = LN2 * (mxa.y + __builtin_amdgcn_logf(sa.y));
    res.z = LN2 * (mxb.x + __builtin_amdgcn_logf(sb.x));
    res.w = LN2 * (mxb.y + __builtin_amdgcn_logf(sb.y));
    ((float4*)out)[gp >> 2] = res;
}

// scalar tail for n % 4 != 0 (not hit for N=2,000,000)
__global__ void gmm_tail_kernel(
    const float* __restrict__ x,
    const float* __restrict__ means,
    const float* __restrict__ cov,
    const float* __restrict__ weights,
    float* __restrict__ out,
    int start, int n)
{
    int i = start + blockIdx.x * blockDim.x + threadIdx.x;
    if (i >= n) return;
    float X = x[3 * i], Y = x[3 * i + 1], Z = x[3 * i + 2];
    float lp[KCOMP];
    float mx = -3.4e38f;
#pragma unroll
    for (int k = 0; k < KCOMP; ++k) {
        float v0 = cov[3 * k] + EPS, v1 = cov[3 * k + 1] + EPS, v2 = cov[3 * k + 2] + EPS;
        float dx = X - means[3 * k], dy = Y - means[3 * k + 1], dz = Z - means[3 * k + 2];
        float q = -2.7568155996140185f
                - 0.5f * (__logf(v0) + __logf(v1) + __logf(v2))
                + __logf(weights[k])
                - 0.5f * (dx * dx / v0 + dy * dy / v1 + dz * dz / v2);
        lp[k] = q;
        mx = fmaxf(mx, q);
    }
    float s = 0.f;
#pragma unroll
    for (int k = 0; k < KCOMP; ++k)
        s += __expf(lp[k] - mx);
    out[i] = mx + __logf(s);
}

extern "C" void kernel_launch(void* const* d_in, const int* in_sizes, int n_in,
                              void* d_out, int out_size, void* d_ws, size_t ws_size,
                              hipStream_t stream) {
    const float* x       = (const float*)d_in[0];
    const float* means   = (const float*)d_in[1];
    const float* cov     = (const float*)d_in[2];
    const float* weights = (const float*)d_in[3];
    float* out           = (float*)d_out;

    const int n = in_sizes[0] / 3;
    const int nmain = n & ~3;
    if (nmain > 0) {
        int blocks = (nmain + 1023) / 1024;    // 1024 points per block
        gmm_loglik_kernel<<<blocks, 256, 0, stream>>>(x, means, cov, weights, out, nmain);
    }
    if (n > nmain) {
        gmm_tail_kernel<<<1, 64, 0, stream>>>(x, means, cov, weights, out, nmain, n);
    }
}